// Round 11
// baseline (436.582 us; speedup 1.0000x reference)
//
#include <hip/hip_runtime.h>
#include <hip/hip_fp16.h>
#include <math.h>

#define N_NODES 100000
#define N_EDGES 3200000
#define HIDDEN 32
#define K_TOP 35
#define NPG 100
#define N_GRAPHS 1000

#define BSHIFT 9
#define NLOC 512                    // nodes per bucket
#define NBUCK 196                   // ceil(100000/512)
#define CAP 17408                   // per-bucket capacity: mean 16384 + 8 sigma
#define NBB 1024                    // bin blocks
#define BIN_CHUNK 13                // 1024*256*13 >= 3.2M

// ---------------- CSR build: single-pass binning into padded buckets ----------------

__global__ void k_bin(const int* __restrict__ src, const int* __restrict__ dst,
                      int* __restrict__ bcnt, unsigned int* __restrict__ bdata) {
    __shared__ int h[NBUCK];
    __shared__ int lbase[NBUCK];
    __shared__ int lcur[NBUCK];
    int t = threadIdx.x;
    for (int i = t; i < NBUCK; i += 256) { h[i] = 0; lcur[i] = 0; }
    __syncthreads();
    int base = blockIdx.x * (256 * BIN_CHUNK);
    int ss[BIN_CHUNK], ds[BIN_CHUNK];
#pragma unroll
    for (int k = 0; k < BIN_CHUNK; k++) {
        int e = base + k * 256 + t;
        if (e < N_EDGES) {
            ss[k] = src[e];
            ds[k] = dst[e];
            atomicAdd(&h[ds[k] >> BSHIFT], 1);
        } else ds[k] = -1;
    }
    __syncthreads();
    for (int i = t; i < NBUCK; i += 256)
        lbase[i] = h[i] ? atomicAdd(&bcnt[i], h[i]) : 0;
    __syncthreads();
#pragma unroll
    for (int k = 0; k < BIN_CHUNK; k++) {
        int d = ds[k];
        if (d >= 0) {
            int bk = d >> BSHIFT;
            int pos = atomicAdd(&lcur[bk], 1);
            bdata[bk * CAP + lbase[bk] + pos] =
                ((unsigned int)ss[k] << BSHIFT) | (unsigned int)(d & (NLOC - 1));
        }
    }
}

// merged: per-bucket counts + within-bucket scan -> rc(int2)/dis, then CSR fill.
__global__ void k_build(const unsigned int* __restrict__ bdata, const int* __restrict__ bcnt,
                        int2* __restrict__ rc, float* __restrict__ dis,
                        int* __restrict__ csr) {
    __shared__ int h[NLOC];
    __shared__ int sd[NLOC];
    __shared__ int rp[NLOC];
    __shared__ int cur[NLOC];
    int b = blockIdx.x, t = threadIdx.x;   // 1024 threads
    if (t < NLOC) h[t] = 0;
    __syncthreads();
    int r0 = b * CAP, r1 = r0 + bcnt[b];
    for (int i = r0 + t; i < r1; i += 1024)
        atomicAdd(&h[bdata[i] & (NLOC - 1)], 1);
    __syncthreads();
    int v = (t < NLOC) ? h[t] : 0;
    if (t < NLOC) sd[t] = v;
    __syncthreads();
    for (int off = 1; off < NLOC; off <<= 1) {
        int x = (t >= off && t < NLOC) ? sd[t - off] : 0;
        __syncthreads();
        if (t < NLOC) sd[t] += x;
        __syncthreads();
    }
    if (t < NLOC) {
        int excl = sd[t] - v;
        int node = (b << BSHIFT) + t;
        rp[t] = r0 + excl;
        cur[t] = 0;
        if (node < N_NODES) {
            rc[node] = make_int2(r0 + excl, v);
            dis[node] = rsqrtf((float)(v + 1));
        }
    }
    __syncthreads();
    for (int i = r0 + t; i < r1; i += 1024) {
        unsigned int u = bdata[i];
        int loc = u & (NLOC - 1);
        int pos = atomicAdd(&cur[loc], 1);
        csr[rp[loc] + pos] = (int)(u >> BSHIFT);
    }
}

// ---------------- GCN layer ----------------

// layer 0: hs[n] (fp16, 64B row) = dis[n] * (x @ w0); 2 nodes/thread.
// Also zeroes both sentinel rows (folds 2 memset dispatches away, ~9 us).
__global__ void k_mm0(const float* __restrict__ in, const float* __restrict__ w,
                      const float* __restrict__ dis, char* __restrict__ hs,
                      char* __restrict__ hsOther) {
    __shared__ float wl[128 * HIDDEN];
    int t = threadIdx.x;
    if (blockIdx.x == 0 && t == 0) {
        float4 z = make_float4(0.f, 0.f, 0.f, 0.f);
        float4* p0 = (float4*)(hs + (size_t)N_NODES * 64);
        float4* p1 = (float4*)(hsOther + (size_t)N_NODES * 64);
#pragma unroll
        for (int q = 0; q < 4; q++) { p0[q] = z; p1[q] = z; }
    }
    for (int i = t; i < 128 * HIDDEN; i += 256) wl[i] = w[i];
    __syncthreads();
    int n0 = blockIdx.x * 512 + t;
    int n1 = n0 + 256;
    bool has0 = n0 < N_NODES, has1 = n1 < N_NODES;
    int m0 = has0 ? n0 : 0, m1 = has1 ? n1 : 0;
    const float* r0p = in + (size_t)m0 * 128;
    const float* r1p = in + (size_t)m1 * 128;
    float acc0[HIDDEN], acc1[HIDDEN];
#pragma unroll
    for (int o = 0; o < HIDDEN; o++) { acc0[o] = 0.f; acc1[o] = 0.f; }
    for (int c4 = 0; c4 < 32; c4++) {
        float4 va = *(const float4*)(r0p + c4 * 4);
        float4 vb = *(const float4*)(r1p + c4 * 4);
        float xa[4] = {va.x, va.y, va.z, va.w};
        float xb[4] = {vb.x, vb.y, vb.z, vb.w};
#pragma unroll
        for (int k = 0; k < 4; k++) {
            const float* wr = &wl[(c4 * 4 + k) * HIDDEN];
#pragma unroll
            for (int o = 0; o < HIDDEN; o++) {
                float wv = wr[o];
                acc0[o] += xa[k] * wv;
                acc1[o] += xb[k] * wv;
            }
        }
    }
    if (has0) {
        float d = dis[m0];
        float4* hr = (float4*)(hs + (size_t)m0 * 64);
#pragma unroll
        for (int qq = 0; qq < 4; qq++) {
            __half2 p[4];
#pragma unroll
            for (int k = 0; k < 4; k++)
                p[k] = __floats2half2_rn(acc0[8 * qq + 2 * k] * d, acc0[8 * qq + 2 * k + 1] * d);
            hr[qq] = *(float4*)p;
        }
    }
    if (has1) {
        float d = dis[m1];
        float4* hr = (float4*)(hs + (size_t)m1 * 64);
#pragma unroll
        for (int qq = 0; qq < 4; qq++) {
            __half2 p[4];
#pragma unroll
            for (int k = 0; k < 4; k++)
                p[k] = __floats2half2_rn(acc1[8 * qq + 2 * k] * d, acc1[8 * qq + 2 * k + 1] * d);
            hr[qq] = *(float4*)p;
        }
    }
}

// fused aggregate + distributed tanh epilogue + next-layer matvec.
// DUAL-NODE half-wave: each half-wave (32 lanes) owns TWO nodes and issues
// 8 independent gathers per 32-edge round (4 per node) -> 2x memory-level
// parallelism (round-10 diagnosis: MLP-limited latency regime; neither VALU
// 55% nor HBM 30% saturated). Per-node accumulation order is bit-identical
// to the proven single-node version (fp32, aA/aB split, sentinel zeros).
// lane c: r=c&3 (16B quad), ph=c>>2 (edge phase / channel-in-quad).
__global__ void k_agg(const float4* __restrict__ hs4, const float* __restrict__ dis,
                      const int2* __restrict__ rc, const int* __restrict__ csr_src,
                      const float* __restrict__ bias,
                      float* __restrict__ feat, int col_off,
                      const float* __restrict__ wnext, char* __restrict__ hsn) {
    __shared__ float wl[32 * 33];
    __shared__ float tv[16][36];
    int tt = threadIdx.x;
    if (wnext) {
        for (int i = tt; i < 1024; i += 256)
            wl[(i >> 5) * 33 + (i & 31)] = wnext[i];
    }
    __syncthreads();
    int g = (blockIdx.x * 256 + tt) >> 5;   // half-wave id; grid covers N_NODES/2
    int n0 = 2 * g, n1 = 2 * g + 1;
    int c = tt & 31;
    int r = c & 3;       // 16B quad within 64B row
    int ph = c >> 2;     // edge phase (0..7) == channel within quad
    int slot = (tt >> 5) * 2;   // tv slots: node0 -> slot, node1 -> slot+1
    int2 rc0 = rc[n0];
    int2 rc1 = rc[n1];
    float d0 = dis[n0], d1 = dis[n1];
    float aA0[8] = {0.f, 0.f, 0.f, 0.f, 0.f, 0.f, 0.f, 0.f};
    float aB0[8] = {0.f, 0.f, 0.f, 0.f, 0.f, 0.f, 0.f, 0.f};
    float aA1[8] = {0.f, 0.f, 0.f, 0.f, 0.f, 0.f, 0.f, 0.f};
    float aB1[8] = {0.f, 0.f, 0.f, 0.f, 0.f, 0.f, 0.f, 0.f};
    int mx = (rc0.y > rc1.y) ? rc0.y : rc1.y;

    for (int base = 0; base < mx; base += 32) {
        int e = base + c;
        // exhausted nodes gather the zeroed sentinel row (fp32 += 0 exact)
        int idx0 = (e < rc0.y) ? csr_src[rc0.x + e] : N_NODES;
        int idx1 = (e < rc1.y) ? csr_src[rc1.x + e] : N_NODES;
        int p00 = __shfl(idx0, ph, 32);
        int p01 = __shfl(idx0, 8 + ph, 32);
        int p02 = __shfl(idx0, 16 + ph, 32);
        int p03 = __shfl(idx0, 24 + ph, 32);
        int p10 = __shfl(idx1, ph, 32);
        int p11 = __shfl(idx1, 8 + ph, 32);
        int p12 = __shfl(idx1, 16 + ph, 32);
        int p13 = __shfl(idx1, 24 + ph, 32);
        float4 g0 = hs4[(size_t)p00 * 4 + r];
        float4 g1 = hs4[(size_t)p01 * 4 + r];
        float4 g2 = hs4[(size_t)p02 * 4 + r];
        float4 g3 = hs4[(size_t)p03 * 4 + r];
        float4 g4 = hs4[(size_t)p10 * 4 + r];
        float4 g5 = hs4[(size_t)p11 * 4 + r];
        float4 g6 = hs4[(size_t)p12 * 4 + r];
        float4 g7 = hs4[(size_t)p13 * 4 + r];
        const __half2* h0 = (const __half2*)&g0;
        const __half2* h1 = (const __half2*)&g1;
        const __half2* h2 = (const __half2*)&g2;
        const __half2* h3 = (const __half2*)&g3;
        const __half2* h4 = (const __half2*)&g4;
        const __half2* h5 = (const __half2*)&g5;
        const __half2* h6 = (const __half2*)&g6;
        const __half2* h7 = (const __half2*)&g7;
        float2 f;
#pragma unroll
        for (int j = 0; j < 4; j++) {
            f = __half22float2(h0[j]); aA0[2 * j] += f.x; aA0[2 * j + 1] += f.y;
        }
#pragma unroll
        for (int j = 0; j < 4; j++) {
            f = __half22float2(h1[j]); aB0[2 * j] += f.x; aB0[2 * j + 1] += f.y;
        }
#pragma unroll
        for (int j = 0; j < 4; j++) {
            f = __half22float2(h2[j]); aA0[2 * j] += f.x; aA0[2 * j + 1] += f.y;
        }
#pragma unroll
        for (int j = 0; j < 4; j++) {
            f = __half22float2(h3[j]); aB0[2 * j] += f.x; aB0[2 * j + 1] += f.y;
        }
#pragma unroll
        for (int j = 0; j < 4; j++) {
            f = __half22float2(h4[j]); aA1[2 * j] += f.x; aA1[2 * j + 1] += f.y;
        }
#pragma unroll
        for (int j = 0; j < 4; j++) {
            f = __half22float2(h5[j]); aB1[2 * j] += f.x; aB1[2 * j + 1] += f.y;
        }
#pragma unroll
        for (int j = 0; j < 4; j++) {
            f = __half22float2(h6[j]); aA1[2 * j] += f.x; aA1[2 * j + 1] += f.y;
        }
#pragma unroll
        for (int j = 0; j < 4; j++) {
            f = __half22float2(h7[j]); aB1[2 * j] += f.x; aB1[2 * j + 1] += f.y;
        }
    }
    float s0[8], s1[8];
#pragma unroll
    for (int k = 0; k < 8; k++) {
        float v = aA0[k] + aB0[k];
        v += __shfl_xor(v, 4);
        v += __shfl_xor(v, 8);
        v += __shfl_xor(v, 16);
        s0[k] = v;
        float u = aA1[k] + aB1[k];
        u += __shfl_xor(u, 4);
        u += __shfl_xor(u, 8);
        u += __shfl_xor(u, 16);
        s1[k] = u;
    }
    // ---- distributed epilogue: lane c handles channel ch = 8r+ph, both nodes ----
    float a01 = (ph & 1) ? s0[1] : s0[0];
    float a23 = (ph & 1) ? s0[3] : s0[2];
    float a45 = (ph & 1) ? s0[5] : s0[4];
    float a67 = (ph & 1) ? s0[7] : s0[6];
    float a03 = (ph & 2) ? a23 : a01;
    float a47 = (ph & 2) ? a67 : a45;
    float sp0 = (ph & 4) ? a47 : a03;
    float b01 = (ph & 1) ? s1[1] : s1[0];
    float b23 = (ph & 1) ? s1[3] : s1[2];
    float b45 = (ph & 1) ? s1[5] : s1[4];
    float b67 = (ph & 1) ? s1[7] : s1[6];
    float b03 = (ph & 2) ? b23 : b01;
    float b47 = (ph & 2) ? b67 : b45;
    float sp1 = (ph & 4) ? b47 : b03;
    // self terms
    float4 sv0 = hs4[(size_t)n0 * 4 + r];
    float4 sv1 = hs4[(size_t)n1 * 4 + r];
    const __half2* sh0 = (const __half2*)&sv0;
    const __half2* sh1 = (const __half2*)&sv1;
    __half2 q01a = (ph & 2) ? sh0[1] : sh0[0];
    __half2 q23a = (ph & 2) ? sh0[3] : sh0[2];
    __half2 qqa  = (ph & 4) ? q23a : q01a;
    float self0 = (ph & 1) ? __high2float(qqa) : __low2float(qqa);
    __half2 q01b = (ph & 2) ? sh1[1] : sh1[0];
    __half2 q23b = (ph & 2) ? sh1[3] : sh1[2];
    __half2 qqb  = (ph & 4) ? q23b : q01b;
    float self1 = (ph & 1) ? __high2float(qqb) : __low2float(qqb);
    int ch = 8 * r + ph;
    float bv = bias[ch];
    float ov0 = tanhf(d0 * (sp0 + self0) + bv);
    float ov1 = tanhf(d1 * (sp1 + self1) + bv);
    __builtin_nontemporal_store(ov0, &feat[(size_t)n0 * 128 + col_off + ch]);
    __builtin_nontemporal_store(ov1, &feat[(size_t)n1 * 128 + col_off + ch]);
    if (wnext) {
        tv[slot][ch] = ov0;       // bijective per slot: conflict-free
        tv[slot + 1][ch] = ov1;
        __builtin_amdgcn_wave_barrier();   // tv writes before reads (same wave)
        float o0 = 0.f, o1 = 0.f;
#pragma unroll 8
        for (int k = 0; k < 32; k++) {
            float wv = wl[k * 33 + c];
            o0 += tv[slot][k] * wv;
            o1 += tv[slot + 1][k] * wv;
        }
        o0 *= d0;
        o1 *= d1;
        float oh0 = __shfl_xor(o0, 1);
        float oh1 = __shfl_xor(o1, 1);
        if ((c & 1) == 0) {
            __half2 pck0 = __floats2half2_rn(o0, oh0);
            __half2 pck1 = __floats2half2_rn(o1, oh1);
            *(__half2*)(hsn + (size_t)n0 * 64 + (size_t)c * 2) = pck0;
            *(__half2*)(hsn + (size_t)n1 * 64 + (size_t)c * 2) = pck1;
        }
    }
}

// ---------------- sort-pool + head (one block per graph) ----------------

__global__ void __launch_bounds__(256, 4)
k_head(const float* __restrict__ feat,
       const float* __restrict__ c1w, const float* __restrict__ c1b,
       const float* __restrict__ c2w, const float* __restrict__ c2b,
       const float* __restrict__ f1w, const float* __restrict__ f1b,
       const float* __restrict__ f2w, const float* __restrict__ f2b,
       float* __restrict__ out) {
    __shared__ float vals[NPG];
    __shared__ int sel[K_TOP];
    __shared__ float tk[K_TOP * 132];
    __shared__ float wl1[16 * 129];
    __shared__ float y1[16][36];
    __shared__ float y2[16][17];
    __shared__ float y3[416];
    __shared__ float y4[128];
    __shared__ float r2[128];
    int g = blockIdx.x, t = threadIdx.x;
    const float* fg = feat + (size_t)g * NPG * 128;

    for (int i = t; i < 2048; i += 256)
        wl1[(i >> 7) * 129 + (i & 127)] = c1w[i];
    if (t < NPG) vals[t] = fg[t * 128 + 127];
    __syncthreads();
    // stable descending rank (matches stable argsort(-v))
    if (t < NPG) {
        float v = vals[t];
        int r = 0;
        for (int j = 0; j < NPG; j++) {
            float u = vals[j];
            r += (u > v) || (u == v && j < t);
        }
        if (r < K_TOP) sel[r] = t;
    }
    __syncthreads();
    for (int i = t; i < K_TOP * 32; i += 256) {
        int k = i >> 5, c4 = i & 31;
        *(float4*)&tk[k * 132 + 4 * c4] = *(const float4*)&fg[sel[k] * 128 + 4 * c4];
    }
    __syncthreads();
    // conv1 (1x1), weights from LDS
    for (int i = t; i < 16 * K_TOP; i += 256) {
        int o = i & 15, k = i >> 4;
        float s = c1b[o];
        const float* wr = &wl1[o * 129];
        const float* xr = &tk[k * 132];
#pragma unroll 8
        for (int c = 0; c < 128; c++) s += wr[c] * xr[c];
        y1[o][k] = fmaxf(s, 0.f);
    }
    __syncthreads();
    // maxpool1d(2): 35 -> 17
    for (int i = t; i < 16 * 17; i += 256) {
        int o = i & 15, l = i >> 4;
        y2[o][l] = fmaxf(y1[o][2 * l], y1[o][2 * l + 1]);
    }
    __syncthreads();
    // conv2 (k=5, VALID): [16,17] -> [32,13]
    for (int idx = t; idx < 32 * 13; idx += 256) {
        int o2 = idx / 13, ttp = idx - o2 * 13;
        float s = c2b[o2];
        const float* wr = c2w + o2 * 80;
#pragma unroll
        for (int i = 0; i < 16; i++)
#pragma unroll
            for (int j = 0; j < 5; j++) s += wr[i * 5 + j] * y2[i][ttp + j];
        y3[idx] = fmaxf(s, 0.f);
    }
    __syncthreads();
    // fc1: 416 -> 128, 2 threads per output, float4 weight loads
    {
        int o = t >> 1, h = t & 1;
        const float4* wr4 = (const float4*)(f1w + o * 416) + h * 52;
        const float* yb = y3 + h * 208;
        float s = 0.f;
#pragma unroll 4
        for (int i = 0; i < 52; i++) {
            float4 w4 = wr4[i];
            s += w4.x * yb[4 * i] + w4.y * yb[4 * i + 1] +
                 w4.z * yb[4 * i + 2] + w4.w * yb[4 * i + 3];
        }
        s += __shfl_xor(s, 1);
        if (h == 0) y4[o] = fmaxf(s + f1b[o], 0.f);
    }
    __syncthreads();
    if (t < 128) r2[t] = f2w[t] * y4[t];
    __syncthreads();
    for (int off = 64; off > 0; off >>= 1) {
        if (t < off) r2[t] += r2[t + off];
        __syncthreads();
    }
    if (t == 0) out[g] = 1.0f / (1.0f + expf(-(r2[0] + f2b[0])));
}

// ---------------- launch ----------------

static inline size_t alignup(size_t x) { return (x + 255) & ~(size_t)255; }

extern "C" void kernel_launch(void* const* d_in, const int* in_sizes, int n_in,
                              void* d_out, int out_size, void* d_ws, size_t ws_size,
                              hipStream_t stream) {
    const float* x    = (const float*)d_in[0];
    const int*   ei   = (const int*)d_in[1];
    const int*   srcp = ei;
    const int*   dstp = ei + N_EDGES;
    const float* w0 = (const float*)d_in[3];
    const float* b0 = (const float*)d_in[4];
    const float* w1 = (const float*)d_in[5];
    const float* b1 = (const float*)d_in[6];
    const float* w2 = (const float*)d_in[7];
    const float* b2 = (const float*)d_in[8];
    const float* w3 = (const float*)d_in[9];
    const float* b3 = (const float*)d_in[10];
    const float* c1w = (const float*)d_in[11];
    const float* c1b = (const float*)d_in[12];
    const float* c2w = (const float*)d_in[13];
    const float* c2b = (const float*)d_in[14];
    const float* f1w = (const float*)d_in[15];
    const float* f1b = (const float*)d_in[16];
    const float* f2w = (const float*)d_in[17];
    const float* f2b = (const float*)d_in[18];
    float* out = (float*)d_out;

    char* p = (char*)d_ws;
    int2* rcv    = (int2*)p; p += alignup(sizeof(int2) * N_NODES);
    float* dis   = (float*)p; p += alignup(sizeof(float) * N_NODES);
    int* bcnt    = (int*)p; p += alignup(sizeof(int) * NBUCK);
    int* csr     = (int*)p; p += alignup(sizeof(int) * (size_t)NBUCK * CAP);
    // union region: bdata (dead after k_build) aliases the two fp16 hs buffers.
    // Each hs buffer gets ONE extra zeroed sentinel row at index N_NODES.
    char* U = p;
    unsigned int* bdata = (unsigned int*)U;
    char* hsA = U;                                             // 6.4 MB fp16 + 64B sentinel
    char* hsB = U + alignup((size_t)N_NODES * 64 + 64);        // 6.4 MB fp16 + 64B sentinel
    size_t usz = alignup(sizeof(unsigned int) * (size_t)NBUCK * CAP); // 13.65 MB
    float* feat = (float*)(U + usz);

    const int NB_M = (N_NODES + 511) / 512;        // 196 (2 nodes/thread)
    const int NB_A = (N_NODES * 16) / 256;         // 6250 (2 nodes per half-wave)

    hipMemsetAsync(bcnt, 0, sizeof(int) * NBUCK, stream);
    k_bin<<<NBB, 256, 0, stream>>>(srcp, dstp, bcnt, bdata);
    k_build<<<NBUCK, 1024, 0, stream>>>(bdata, bcnt, rcv, dis, csr);

    // k_mm0 zeroes both sentinel rows (saves 2 memset dispatches ~9 us)
    k_mm0<<<NB_M, 256, 0, stream>>>(x, w0, dis, hsA, hsB);
    k_agg<<<NB_A, 256, 0, stream>>>((const float4*)hsA, dis, rcv, csr, b0,
                                    feat, 0, w1, hsB);
    k_agg<<<NB_A, 256, 0, stream>>>((const float4*)hsB, dis, rcv, csr, b1,
                                    feat, 32, w2, hsA);
    k_agg<<<NB_A, 256, 0, stream>>>((const float4*)hsA, dis, rcv, csr, b2,
                                    feat, 64, w3, hsB);
    k_agg<<<NB_A, 256, 0, stream>>>((const float4*)hsB, dis, rcv, csr, b3,
                                    feat, 96, (const float*)nullptr, (char*)nullptr);

    k_head<<<N_GRAPHS, 256, 0, stream>>>(feat, c1w, c1b, c2w, c2b,
                                         f1w, f1b, f2w, f2b, out);
}

// Round 12
// 422.771 us; speedup vs baseline: 1.0327x; 1.0327x over previous
//
#include <hip/hip_runtime.h>
#include <hip/hip_fp16.h>
#include <math.h>

#define N_NODES 100000
#define N_EDGES 3200000
#define HIDDEN 32
#define K_TOP 35
#define NPG 100
#define N_GRAPHS 1000

#define BSHIFT 8
#define NLOC 256                    // nodes per bucket
#define NBUCK 391                   // ceil(100000/256)
#define CAP 8960                    // per-bucket capacity: mean 8192 + 8.5 sigma
#define NBB 1024                    // bin blocks
#define BIN_CHUNK 13                // 1024*256*13 >= 3.2M

// ---------------- CSR build: single-pass binning into padded buckets ----------------
// BSHIFT 9->8 (r12): 391 buckets -> k_build fills all 256 CUs (was 196 blocks,
// 23% idle) and halves LDS-atomic same-address contention in both kernels.

__global__ void k_bin(const int* __restrict__ src, const int* __restrict__ dst,
                      int* __restrict__ bcnt, unsigned int* __restrict__ bdata) {
    __shared__ int h[NBUCK];
    __shared__ int lbase[NBUCK];
    __shared__ int lcur[NBUCK];
    int t = threadIdx.x;
    for (int i = t; i < NBUCK; i += 256) { h[i] = 0; lcur[i] = 0; }
    __syncthreads();
    int base = blockIdx.x * (256 * BIN_CHUNK);
    int ss[BIN_CHUNK], ds[BIN_CHUNK];
#pragma unroll
    for (int k = 0; k < BIN_CHUNK; k++) {
        int e = base + k * 256 + t;
        if (e < N_EDGES) {
            ss[k] = src[e];
            ds[k] = dst[e];
            atomicAdd(&h[ds[k] >> BSHIFT], 1);
        } else ds[k] = -1;
    }
    __syncthreads();
    for (int i = t; i < NBUCK; i += 256)
        lbase[i] = h[i] ? atomicAdd(&bcnt[i], h[i]) : 0;
    __syncthreads();
#pragma unroll
    for (int k = 0; k < BIN_CHUNK; k++) {
        int d = ds[k];
        if (d >= 0) {
            int bk = d >> BSHIFT;
            int pos = atomicAdd(&lcur[bk], 1);
            bdata[bk * CAP + lbase[bk] + pos] =
                ((unsigned int)ss[k] << BSHIFT) | (unsigned int)(d & (NLOC - 1));
        }
    }
}

// merged: per-bucket counts + within-bucket scan -> rc(int2)/dis, then CSR fill.
__global__ void k_build(const unsigned int* __restrict__ bdata, const int* __restrict__ bcnt,
                        int2* __restrict__ rc, float* __restrict__ dis,
                        int* __restrict__ csr) {
    __shared__ int h[NLOC];
    __shared__ int sd[NLOC];
    __shared__ int rp[NLOC];
    __shared__ int cur[NLOC];
    int b = blockIdx.x, t = threadIdx.x;   // 1024 threads
    if (t < NLOC) h[t] = 0;
    __syncthreads();
    int r0 = b * CAP, r1 = r0 + bcnt[b];
    for (int i = r0 + t; i < r1; i += 1024)
        atomicAdd(&h[bdata[i] & (NLOC - 1)], 1);
    __syncthreads();
    int v = (t < NLOC) ? h[t] : 0;
    if (t < NLOC) sd[t] = v;
    __syncthreads();
    for (int off = 1; off < NLOC; off <<= 1) {
        int x = (t >= off && t < NLOC) ? sd[t - off] : 0;
        __syncthreads();
        if (t < NLOC) sd[t] += x;
        __syncthreads();
    }
    if (t < NLOC) {
        int excl = sd[t] - v;
        int node = (b << BSHIFT) + t;
        rp[t] = r0 + excl;
        cur[t] = 0;
        if (node < N_NODES) {
            rc[node] = make_int2(r0 + excl, v);
            dis[node] = rsqrtf((float)(v + 1));
        }
    }
    __syncthreads();
    for (int i = r0 + t; i < r1; i += 1024) {
        unsigned int u = bdata[i];
        int loc = u & (NLOC - 1);
        int pos = atomicAdd(&cur[loc], 1);
        csr[rp[loc] + pos] = (int)(u >> BSHIFT);
    }
}

// ---------------- GCN layer ----------------

// layer 0: hs[n] (fp16, 64B row) = dis[n] * (x @ w0); 2 nodes/thread.
// Also zeroes both sentinel rows (folds 2 memset dispatches away, ~9 us).
__global__ void k_mm0(const float* __restrict__ in, const float* __restrict__ w,
                      const float* __restrict__ dis, char* __restrict__ hs,
                      char* __restrict__ hsOther) {
    __shared__ float wl[128 * HIDDEN];
    int t = threadIdx.x;
    if (blockIdx.x == 0 && t == 0) {
        float4 z = make_float4(0.f, 0.f, 0.f, 0.f);
        float4* p0 = (float4*)(hs + (size_t)N_NODES * 64);
        float4* p1 = (float4*)(hsOther + (size_t)N_NODES * 64);
#pragma unroll
        for (int q = 0; q < 4; q++) { p0[q] = z; p1[q] = z; }
    }
    for (int i = t; i < 128 * HIDDEN; i += 256) wl[i] = w[i];
    __syncthreads();
    int n0 = blockIdx.x * 512 + t;
    int n1 = n0 + 256;
    bool has0 = n0 < N_NODES, has1 = n1 < N_NODES;
    int m0 = has0 ? n0 : 0, m1 = has1 ? n1 : 0;
    const float* r0p = in + (size_t)m0 * 128;
    const float* r1p = in + (size_t)m1 * 128;
    float acc0[HIDDEN], acc1[HIDDEN];
#pragma unroll
    for (int o = 0; o < HIDDEN; o++) { acc0[o] = 0.f; acc1[o] = 0.f; }
    for (int c4 = 0; c4 < 32; c4++) {
        float4 va = *(const float4*)(r0p + c4 * 4);
        float4 vb = *(const float4*)(r1p + c4 * 4);
        float xa[4] = {va.x, va.y, va.z, va.w};
        float xb[4] = {vb.x, vb.y, vb.z, vb.w};
#pragma unroll
        for (int k = 0; k < 4; k++) {
            const float* wr = &wl[(c4 * 4 + k) * HIDDEN];
#pragma unroll
            for (int o = 0; o < HIDDEN; o++) {
                float wv = wr[o];
                acc0[o] += xa[k] * wv;
                acc1[o] += xb[k] * wv;
            }
        }
    }
    if (has0) {
        float d = dis[m0];
        float4* hr = (float4*)(hs + (size_t)m0 * 64);
#pragma unroll
        for (int qq = 0; qq < 4; qq++) {
            __half2 p[4];
#pragma unroll
            for (int k = 0; k < 4; k++)
                p[k] = __floats2half2_rn(acc0[8 * qq + 2 * k] * d, acc0[8 * qq + 2 * k + 1] * d);
            hr[qq] = *(float4*)p;
        }
    }
    if (has1) {
        float d = dis[m1];
        float4* hr = (float4*)(hs + (size_t)m1 * 64);
#pragma unroll
        for (int qq = 0; qq < 4; qq++) {
            __half2 p[4];
#pragma unroll
            for (int k = 0; k < 4; k++)
                p[k] = __floats2half2_rn(acc1[8 * qq + 2 * k] * d, acc1[8 * qq + 2 * k + 1] * d);
            hr[qq] = *(float4*)p;
        }
    }
}

// fused aggregate + distributed tanh epilogue + next-layer matvec (round-10
// proven best: 64B rows, half-wave per node, 32-edge rounds, fp32 accum,
// sentinel de-predication, software-pipelined csr prefetch).
// lane c: r=c&3 (16B quad), ph=c>>2 (edge phase / channel-in-quad).
__global__ void k_agg(const float4* __restrict__ hs4, const float* __restrict__ dis,
                      const int2* __restrict__ rc, const int* __restrict__ csr_src,
                      const float* __restrict__ bias,
                      float* __restrict__ feat, int col_off,
                      const float* __restrict__ wnext, char* __restrict__ hsn) {
    __shared__ float wl[32 * 33];
    __shared__ float tv[8][36];
    int tt = threadIdx.x;
    if (wnext) {
        for (int i = tt; i < 1024; i += 256)
            wl[(i >> 5) * 33 + (i & 31)] = wnext[i];
    }
    __syncthreads();
    int n = (blockIdx.x * 256 + tt) >> 5;   // grid covers exactly N_NODES*32 lanes
    int c = tt & 31;
    int r = c & 3;       // 16B quad within 64B row
    int ph = c >> 2;     // edge phase (0..7) == channel within quad
    int slot = tt >> 5;
    int2 rcv = rc[n];
    int start = rcv.x, m = rcv.y;
    float d = dis[n];
    float aA[8] = {0.f, 0.f, 0.f, 0.f, 0.f, 0.f, 0.f, 0.f};
    float aB[8] = {0.f, 0.f, 0.f, 0.f, 0.f, 0.f, 0.f, 0.f};

    if (m > 0) {
        int idx = (c < m) ? csr_src[start + c] : N_NODES;
        for (int base = 0;;) {
            int nb = base + 32;
            // prefetch next round's indices before this round's gathers
            int idxn = (nb + c < m) ? csr_src[start + nb + c] : N_NODES;
            int id0 = __shfl(idx, ph, 32);
            int id1 = __shfl(idx, 8 + ph, 32);
            int id2 = __shfl(idx, 16 + ph, 32);
            int id3 = __shfl(idx, 24 + ph, 32);
            float4 g0 = hs4[(size_t)id0 * 4 + r];
            float4 g1 = hs4[(size_t)id1 * 4 + r];
            float4 g2 = hs4[(size_t)id2 * 4 + r];
            float4 g3 = hs4[(size_t)id3 * 4 + r];
            const __half2* h0 = (const __half2*)&g0;
            const __half2* h1 = (const __half2*)&g1;
            const __half2* h2 = (const __half2*)&g2;
            const __half2* h3 = (const __half2*)&g3;
            float2 f;
#pragma unroll
            for (int j = 0; j < 4; j++) {
                f = __half22float2(h0[j]); aA[2 * j] += f.x; aA[2 * j + 1] += f.y;
            }
#pragma unroll
            for (int j = 0; j < 4; j++) {
                f = __half22float2(h1[j]); aB[2 * j] += f.x; aB[2 * j + 1] += f.y;
            }
#pragma unroll
            for (int j = 0; j < 4; j++) {
                f = __half22float2(h2[j]); aA[2 * j] += f.x; aA[2 * j + 1] += f.y;
            }
#pragma unroll
            for (int j = 0; j < 4; j++) {
                f = __half22float2(h3[j]); aB[2 * j] += f.x; aB[2 * j + 1] += f.y;
            }
            if (nb >= m) break;
            idx = idxn;
            base = nb;
        }
    }
    float s[8];
#pragma unroll
    for (int k = 0; k < 8; k++) {
        float v = aA[k] + aB[k];
        v += __shfl_xor(v, 4);
        v += __shfl_xor(v, 8);
        v += __shfl_xor(v, 16);
        s[k] = v;   // every lane: full sums for channels 8r..8r+7
    }
    // ---- distributed epilogue: lane c handles channel ch = 8r+ph ----
    float s01 = (ph & 1) ? s[1] : s[0];
    float s23 = (ph & 1) ? s[3] : s[2];
    float s45 = (ph & 1) ? s[5] : s[4];
    float s67 = (ph & 1) ? s[7] : s[6];
    float s03 = (ph & 2) ? s23 : s01;
    float s47 = (ph & 2) ? s67 : s45;
    float sp  = (ph & 4) ? s47 : s03;
    // self term: element ph of the node's quad r
    float4 sv = hs4[(size_t)n * 4 + r];
    const __half2* sh = (const __half2*)&sv;
    __half2 q01 = (ph & 2) ? sh[1] : sh[0];
    __half2 q23 = (ph & 2) ? sh[3] : sh[2];
    __half2 qq  = (ph & 4) ? q23 : q01;
    float self = (ph & 1) ? __high2float(qq) : __low2float(qq);
    float bv = bias[8 * r + ph];
    float ov = tanhf(d * (sp + self) + bv);
    __builtin_nontemporal_store(ov, &feat[(size_t)n * 128 + col_off + 8 * r + ph]);
    if (wnext) {
        tv[slot][8 * r + ph] = ov;   // bijective index: conflict-free
        __builtin_amdgcn_wave_barrier();   // tv writes before reads (same wave)
        float o = 0.f;
#pragma unroll 8
        for (int k = 0; k < 32; k++)
            o += tv[slot][k] * wl[k * 33 + c];
        o *= d;
        float oh = __shfl_xor(o, 1);
        if ((c & 1) == 0) {
            __half2 pck = __floats2half2_rn(o, oh);
            *(__half2*)(hsn + (size_t)n * 64 + (size_t)c * 2) = pck;
        }
    }
}

// ---------------- sort-pool + head (one block per graph) ----------------

__global__ void __launch_bounds__(256, 4)
k_head(const float* __restrict__ feat,
       const float* __restrict__ c1w, const float* __restrict__ c1b,
       const float* __restrict__ c2w, const float* __restrict__ c2b,
       const float* __restrict__ f1w, const float* __restrict__ f1b,
       const float* __restrict__ f2w, const float* __restrict__ f2b,
       float* __restrict__ out) {
    __shared__ float vals[NPG];
    __shared__ int sel[K_TOP];
    __shared__ float tk[K_TOP * 132];
    __shared__ float wl1[16 * 129];
    __shared__ float y1[16][36];
    __shared__ float y2[16][17];
    __shared__ float y3[416];
    __shared__ float y4[128];
    __shared__ float r2[128];
    int g = blockIdx.x, t = threadIdx.x;
    const float* fg = feat + (size_t)g * NPG * 128;

    for (int i = t; i < 2048; i += 256)
        wl1[(i >> 7) * 129 + (i & 127)] = c1w[i];
    if (t < NPG) vals[t] = fg[t * 128 + 127];
    __syncthreads();
    // stable descending rank (matches stable argsort(-v))
    if (t < NPG) {
        float v = vals[t];
        int r = 0;
        for (int j = 0; j < NPG; j++) {
            float u = vals[j];
            r += (u > v) || (u == v && j < t);
        }
        if (r < K_TOP) sel[r] = t;
    }
    __syncthreads();
    for (int i = t; i < K_TOP * 32; i += 256) {
        int k = i >> 5, c4 = i & 31;
        *(float4*)&tk[k * 132 + 4 * c4] = *(const float4*)&fg[sel[k] * 128 + 4 * c4];
    }
    __syncthreads();
    // conv1 (1x1), weights from LDS
    for (int i = t; i < 16 * K_TOP; i += 256) {
        int o = i & 15, k = i >> 4;
        float s = c1b[o];
        const float* wr = &wl1[o * 129];
        const float* xr = &tk[k * 132];
#pragma unroll 8
        for (int c = 0; c < 128; c++) s += wr[c] * xr[c];
        y1[o][k] = fmaxf(s, 0.f);
    }
    __syncthreads();
    // maxpool1d(2): 35 -> 17
    for (int i = t; i < 16 * 17; i += 256) {
        int o = i & 15, l = i >> 4;
        y2[o][l] = fmaxf(y1[o][2 * l], y1[o][2 * l + 1]);
    }
    __syncthreads();
    // conv2 (k=5, VALID): [16,17] -> [32,13]
    for (int idx = t; idx < 32 * 13; idx += 256) {
        int o2 = idx / 13, ttp = idx - o2 * 13;
        float s = c2b[o2];
        const float* wr = c2w + o2 * 80;
#pragma unroll
        for (int i = 0; i < 16; i++)
#pragma unroll
            for (int j = 0; j < 5; j++) s += wr[i * 5 + j] * y2[i][ttp + j];
        y3[idx] = fmaxf(s, 0.f);
    }
    __syncthreads();
    // fc1: 416 -> 128, 2 threads per output, float4 weight loads
    {
        int o = t >> 1, h = t & 1;
        const float4* wr4 = (const float4*)(f1w + o * 416) + h * 52;
        const float* yb = y3 + h * 208;
        float s = 0.f;
#pragma unroll 4
        for (int i = 0; i < 52; i++) {
            float4 w4 = wr4[i];
            s += w4.x * yb[4 * i] + w4.y * yb[4 * i + 1] +
                 w4.z * yb[4 * i + 2] + w4.w * yb[4 * i + 3];
        }
        s += __shfl_xor(s, 1);
        if (h == 0) y4[o] = fmaxf(s + f1b[o], 0.f);
    }
    __syncthreads();
    if (t < 128) r2[t] = f2w[t] * y4[t];
    __syncthreads();
    for (int off = 64; off > 0; off >>= 1) {
        if (t < off) r2[t] += r2[t + off];
        __syncthreads();
    }
    if (t == 0) out[g] = 1.0f / (1.0f + expf(-(r2[0] + f2b[0])));
}

// ---------------- launch ----------------

static inline size_t alignup(size_t x) { return (x + 255) & ~(size_t)255; }

extern "C" void kernel_launch(void* const* d_in, const int* in_sizes, int n_in,
                              void* d_out, int out_size, void* d_ws, size_t ws_size,
                              hipStream_t stream) {
    const float* x    = (const float*)d_in[0];
    const int*   ei   = (const int*)d_in[1];
    const int*   srcp = ei;
    const int*   dstp = ei + N_EDGES;
    const float* w0 = (const float*)d_in[3];
    const float* b0 = (const float*)d_in[4];
    const float* w1 = (const float*)d_in[5];
    const float* b1 = (const float*)d_in[6];
    const float* w2 = (const float*)d_in[7];
    const float* b2 = (const float*)d_in[8];
    const float* w3 = (const float*)d_in[9];
    const float* b3 = (const float*)d_in[10];
    const float* c1w = (const float*)d_in[11];
    const float* c1b = (const float*)d_in[12];
    const float* c2w = (const float*)d_in[13];
    const float* c2b = (const float*)d_in[14];
    const float* f1w = (const float*)d_in[15];
    const float* f1b = (const float*)d_in[16];
    const float* f2w = (const float*)d_in[17];
    const float* f2b = (const float*)d_in[18];
    float* out = (float*)d_out;

    char* p = (char*)d_ws;
    int2* rcv    = (int2*)p; p += alignup(sizeof(int2) * N_NODES);
    float* dis   = (float*)p; p += alignup(sizeof(float) * N_NODES);
    int* bcnt    = (int*)p; p += alignup(sizeof(int) * NBUCK);
    int* csr     = (int*)p; p += alignup(sizeof(int) * (size_t)NBUCK * CAP);
    // union region: bdata (dead after k_build) aliases the two fp16 hs buffers.
    // Each hs buffer gets ONE extra zeroed sentinel row at index N_NODES.
    char* U = p;
    unsigned int* bdata = (unsigned int*)U;
    char* hsA = U;                                             // 6.4 MB fp16 + 64B sentinel
    char* hsB = U + alignup((size_t)N_NODES * 64 + 64);        // 6.4 MB fp16 + 64B sentinel
    size_t usz = alignup(sizeof(unsigned int) * (size_t)NBUCK * CAP); // 14.0 MB
    float* feat = (float*)(U + usz);

    const int NB_M = (N_NODES + 511) / 512;        // 196 (2 nodes/thread)
    const int NB_A = (N_NODES * 32) / 256;         // 12500 (exact, half-wave per node)

    hipMemsetAsync(bcnt, 0, sizeof(int) * NBUCK, stream);
    k_bin<<<NBB, 256, 0, stream>>>(srcp, dstp, bcnt, bdata);
    k_build<<<NBUCK, 1024, 0, stream>>>(bdata, bcnt, rcv, dis, csr);

    // k_mm0 zeroes both sentinel rows (saves 2 memset dispatches ~9 us)
    k_mm0<<<NB_M, 256, 0, stream>>>(x, w0, dis, hsA, hsB);
    k_agg<<<NB_A, 256, 0, stream>>>((const float4*)hsA, dis, rcv, csr, b0,
                                    feat, 0, w1, hsB);
    k_agg<<<NB_A, 256, 0, stream>>>((const float4*)hsB, dis, rcv, csr, b1,
                                    feat, 32, w2, hsA);
    k_agg<<<NB_A, 256, 0, stream>>>((const float4*)hsA, dis, rcv, csr, b2,
                                    feat, 64, w3, hsB);
    k_agg<<<NB_A, 256, 0, stream>>>((const float4*)hsB, dis, rcv, csr, b3,
                                    feat, 96, (const float*)nullptr, (char*)nullptr);

    k_head<<<N_GRAPHS, 256, 0, stream>>>(feat, c1w, c1b, c2w, c2b,
                                         f1w, f1b, f2w, f2b, out);
}

// Round 13
// 410.278 us; speedup vs baseline: 1.0641x; 1.0304x over previous
//
#include <hip/hip_runtime.h>
#include <hip/hip_fp16.h>
#include <math.h>

#define N_NODES 100000
#define N_EDGES 3200000
#define HIDDEN 32
#define K_TOP 35
#define NPG 100
#define N_GRAPHS 1000

#define BSHIFT 9
#define NLOC 512                    // nodes per bucket
#define NBUCK 196                   // ceil(100000/512)
#define CAP 17408                   // per-bucket capacity: mean 16384 + 8 sigma
#define NBB 512                     // bin blocks (fewer, fatter -> longer runs)
#define BIN_CHUNK 25                // 512*256*25 = 3.2768M >= 3.2M

// ---------------- CSR build: single-pass binning into padded buckets ----------------
// r12 measurement: bdata scatter is write-allocate bound (82 MB writeback for
// 13 MB logical at 8.5-entry runs). Longer runs per bucket = fewer partial-line
// boundaries: NBB 1024->512 doubles run length (17->33 entries, 131 B). src is
// re-read in the scatter phase (edge list is L3-resident: FETCH 12.5 MB < one
// read) instead of held in registers.

__global__ void k_bin(const int* __restrict__ src, const int* __restrict__ dst,
                      int* __restrict__ bcnt, unsigned int* __restrict__ bdata) {
    __shared__ int h[NBUCK];
    __shared__ int lbase[NBUCK];
    __shared__ int lcur[NBUCK];
    int t = threadIdx.x;
    for (int i = t; i < NBUCK; i += 256) { h[i] = 0; lcur[i] = 0; }
    __syncthreads();
    int base = blockIdx.x * (256 * BIN_CHUNK);
    int ds[BIN_CHUNK];
#pragma unroll
    for (int k = 0; k < BIN_CHUNK; k++) {
        int e = base + k * 256 + t;
        ds[k] = (e < N_EDGES) ? dst[e] : -1;
    }
#pragma unroll
    for (int k = 0; k < BIN_CHUNK; k++)
        if (ds[k] >= 0) atomicAdd(&h[ds[k] >> BSHIFT], 1);
    __syncthreads();
    for (int i = t; i < NBUCK; i += 256)
        lbase[i] = h[i] ? atomicAdd(&bcnt[i], h[i]) : 0;
    __syncthreads();
#pragma unroll
    for (int k = 0; k < BIN_CHUNK; k++) {
        int d = ds[k];
        if (d >= 0) {
            int e = base + k * 256 + t;
            int s = src[e];                      // L3-hot re-read
            int bk = d >> BSHIFT;
            int pos = atomicAdd(&lcur[bk], 1);
            bdata[bk * CAP + lbase[bk] + pos] =
                ((unsigned int)s << BSHIFT) | (unsigned int)(d & (NLOC - 1));
        }
    }
}

// merged: per-bucket counts + within-bucket scan -> rc(int2)/dis, then CSR fill.
__global__ void k_build(const unsigned int* __restrict__ bdata, const int* __restrict__ bcnt,
                        int2* __restrict__ rc, float* __restrict__ dis,
                        int* __restrict__ csr) {
    __shared__ int h[NLOC];
    __shared__ int sd[NLOC];
    __shared__ int rp[NLOC];
    __shared__ int cur[NLOC];
    int b = blockIdx.x, t = threadIdx.x;   // 1024 threads
    if (t < NLOC) h[t] = 0;
    __syncthreads();
    int r0 = b * CAP, r1 = r0 + bcnt[b];
    for (int i = r0 + t; i < r1; i += 1024)
        atomicAdd(&h[bdata[i] & (NLOC - 1)], 1);
    __syncthreads();
    int v = (t < NLOC) ? h[t] : 0;
    if (t < NLOC) sd[t] = v;
    __syncthreads();
    for (int off = 1; off < NLOC; off <<= 1) {
        int x = (t >= off && t < NLOC) ? sd[t - off] : 0;
        __syncthreads();
        if (t < NLOC) sd[t] += x;
        __syncthreads();
    }
    if (t < NLOC) {
        int excl = sd[t] - v;
        int node = (b << BSHIFT) + t;
        rp[t] = r0 + excl;
        cur[t] = 0;
        if (node < N_NODES) {
            rc[node] = make_int2(r0 + excl, v);
            dis[node] = rsqrtf((float)(v + 1));
        }
    }
    __syncthreads();
    for (int i = r0 + t; i < r1; i += 1024) {
        unsigned int u = bdata[i];
        int loc = u & (NLOC - 1);
        int pos = atomicAdd(&cur[loc], 1);
        csr[rp[loc] + pos] = (int)(u >> BSHIFT);
    }
}

// ---------------- GCN layer ----------------

// layer 0: hs[n] (fp16, 64B row) = dis[n] * (x @ w0); 2 nodes/thread.
// Also zeroes both sentinel rows (folds 2 memset dispatches away, ~9 us).
__global__ void k_mm0(const float* __restrict__ in, const float* __restrict__ w,
                      const float* __restrict__ dis, char* __restrict__ hs,
                      char* __restrict__ hsOther) {
    __shared__ float wl[128 * HIDDEN];
    int t = threadIdx.x;
    if (blockIdx.x == 0 && t == 0) {
        float4 z = make_float4(0.f, 0.f, 0.f, 0.f);
        float4* p0 = (float4*)(hs + (size_t)N_NODES * 64);
        float4* p1 = (float4*)(hsOther + (size_t)N_NODES * 64);
#pragma unroll
        for (int q = 0; q < 4; q++) { p0[q] = z; p1[q] = z; }
    }
    for (int i = t; i < 128 * HIDDEN; i += 256) wl[i] = w[i];
    __syncthreads();
    int n0 = blockIdx.x * 512 + t;
    int n1 = n0 + 256;
    bool has0 = n0 < N_NODES, has1 = n1 < N_NODES;
    int m0 = has0 ? n0 : 0, m1 = has1 ? n1 : 0;
    const float* r0p = in + (size_t)m0 * 128;
    const float* r1p = in + (size_t)m1 * 128;
    float acc0[HIDDEN], acc1[HIDDEN];
#pragma unroll
    for (int o = 0; o < HIDDEN; o++) { acc0[o] = 0.f; acc1[o] = 0.f; }
    for (int c4 = 0; c4 < 32; c4++) {
        float4 va = *(const float4*)(r0p + c4 * 4);
        float4 vb = *(const float4*)(r1p + c4 * 4);
        float xa[4] = {va.x, va.y, va.z, va.w};
        float xb[4] = {vb.x, vb.y, vb.z, vb.w};
#pragma unroll
        for (int k = 0; k < 4; k++) {
            const float* wr = &wl[(c4 * 4 + k) * HIDDEN];
#pragma unroll
            for (int o = 0; o < HIDDEN; o++) {
                float wv = wr[o];
                acc0[o] += xa[k] * wv;
                acc1[o] += xb[k] * wv;
            }
        }
    }
    if (has0) {
        float d = dis[m0];
        float4* hr = (float4*)(hs + (size_t)m0 * 64);
#pragma unroll
        for (int qq = 0; qq < 4; qq++) {
            __half2 p[4];
#pragma unroll
            for (int k = 0; k < 4; k++)
                p[k] = __floats2half2_rn(acc0[8 * qq + 2 * k] * d, acc0[8 * qq + 2 * k + 1] * d);
            hr[qq] = *(float4*)p;
        }
    }
    if (has1) {
        float d = dis[m1];
        float4* hr = (float4*)(hs + (size_t)m1 * 64);
#pragma unroll
        for (int qq = 0; qq < 4; qq++) {
            __half2 p[4];
#pragma unroll
            for (int k = 0; k < 4; k++)
                p[k] = __floats2half2_rn(acc1[8 * qq + 2 * k] * d, acc1[8 * qq + 2 * k + 1] * d);
            hr[qq] = *(float4*)p;
        }
    }
}

// fused aggregate + distributed tanh epilogue + next-layer matvec (round-10
// proven best: 64B rows, half-wave per node, 32-edge rounds, fp32 accum,
// sentinel de-predication, software-pipelined csr prefetch).
// lane c: r=c&3 (16B quad), ph=c>>2 (edge phase / channel-in-quad).
__global__ void k_agg(const float4* __restrict__ hs4, const float* __restrict__ dis,
                      const int2* __restrict__ rc, const int* __restrict__ csr_src,
                      const float* __restrict__ bias,
                      float* __restrict__ feat, int col_off,
                      const float* __restrict__ wnext, char* __restrict__ hsn) {
    __shared__ float wl[32 * 33];
    __shared__ float tv[8][36];
    int tt = threadIdx.x;
    if (wnext) {
        for (int i = tt; i < 1024; i += 256)
            wl[(i >> 5) * 33 + (i & 31)] = wnext[i];
    }
    __syncthreads();
    int n = (blockIdx.x * 256 + tt) >> 5;   // grid covers exactly N_NODES*32 lanes
    int c = tt & 31;
    int r = c & 3;       // 16B quad within 64B row
    int ph = c >> 2;     // edge phase (0..7) == channel within quad
    int slot = tt >> 5;
    int2 rcv = rc[n];
    int start = rcv.x, m = rcv.y;
    float d = dis[n];
    float aA[8] = {0.f, 0.f, 0.f, 0.f, 0.f, 0.f, 0.f, 0.f};
    float aB[8] = {0.f, 0.f, 0.f, 0.f, 0.f, 0.f, 0.f, 0.f};

    if (m > 0) {
        int idx = (c < m) ? csr_src[start + c] : N_NODES;
        for (int base = 0;;) {
            int nb = base + 32;
            // prefetch next round's indices before this round's gathers
            int idxn = (nb + c < m) ? csr_src[start + nb + c] : N_NODES;
            int id0 = __shfl(idx, ph, 32);
            int id1 = __shfl(idx, 8 + ph, 32);
            int id2 = __shfl(idx, 16 + ph, 32);
            int id3 = __shfl(idx, 24 + ph, 32);
            float4 g0 = hs4[(size_t)id0 * 4 + r];
            float4 g1 = hs4[(size_t)id1 * 4 + r];
            float4 g2 = hs4[(size_t)id2 * 4 + r];
            float4 g3 = hs4[(size_t)id3 * 4 + r];
            const __half2* h0 = (const __half2*)&g0;
            const __half2* h1 = (const __half2*)&g1;
            const __half2* h2 = (const __half2*)&g2;
            const __half2* h3 = (const __half2*)&g3;
            float2 f;
#pragma unroll
            for (int j = 0; j < 4; j++) {
                f = __half22float2(h0[j]); aA[2 * j] += f.x; aA[2 * j + 1] += f.y;
            }
#pragma unroll
            for (int j = 0; j < 4; j++) {
                f = __half22float2(h1[j]); aB[2 * j] += f.x; aB[2 * j + 1] += f.y;
            }
#pragma unroll
            for (int j = 0; j < 4; j++) {
                f = __half22float2(h2[j]); aA[2 * j] += f.x; aA[2 * j + 1] += f.y;
            }
#pragma unroll
            for (int j = 0; j < 4; j++) {
                f = __half22float2(h3[j]); aB[2 * j] += f.x; aB[2 * j + 1] += f.y;
            }
            if (nb >= m) break;
            idx = idxn;
            base = nb;
        }
    }
    float s[8];
#pragma unroll
    for (int k = 0; k < 8; k++) {
        float v = aA[k] + aB[k];
        v += __shfl_xor(v, 4);
        v += __shfl_xor(v, 8);
        v += __shfl_xor(v, 16);
        s[k] = v;   // every lane: full sums for channels 8r..8r+7
    }
    // ---- distributed epilogue: lane c handles channel ch = 8r+ph ----
    float s01 = (ph & 1) ? s[1] : s[0];
    float s23 = (ph & 1) ? s[3] : s[2];
    float s45 = (ph & 1) ? s[5] : s[4];
    float s67 = (ph & 1) ? s[7] : s[6];
    float s03 = (ph & 2) ? s23 : s01;
    float s47 = (ph & 2) ? s67 : s45;
    float sp  = (ph & 4) ? s47 : s03;
    // self term: element ph of the node's quad r
    float4 sv = hs4[(size_t)n * 4 + r];
    const __half2* sh = (const __half2*)&sv;
    __half2 q01 = (ph & 2) ? sh[1] : sh[0];
    __half2 q23 = (ph & 2) ? sh[3] : sh[2];
    __half2 qq  = (ph & 4) ? q23 : q01;
    float self = (ph & 1) ? __high2float(qq) : __low2float(qq);
    float bv = bias[8 * r + ph];
    float ov = tanhf(d * (sp + self) + bv);
    __builtin_nontemporal_store(ov, &feat[(size_t)n * 128 + col_off + 8 * r + ph]);
    if (wnext) {
        tv[slot][8 * r + ph] = ov;   // bijective index: conflict-free
        __builtin_amdgcn_wave_barrier();   // tv writes before reads (same wave)
        float o = 0.f;
#pragma unroll 8
        for (int k = 0; k < 32; k++)
            o += tv[slot][k] * wl[k * 33 + c];
        o *= d;
        float oh = __shfl_xor(o, 1);
        if ((c & 1) == 0) {
            __half2 pck = __floats2half2_rn(o, oh);
            *(__half2*)(hsn + (size_t)n * 64 + (size_t)c * 2) = pck;
        }
    }
}

// ---------------- sort-pool + head (one block per graph) ----------------

__global__ void __launch_bounds__(256, 4)
k_head(const float* __restrict__ feat,
       const float* __restrict__ c1w, const float* __restrict__ c1b,
       const float* __restrict__ c2w, const float* __restrict__ c2b,
       const float* __restrict__ f1w, const float* __restrict__ f1b,
       const float* __restrict__ f2w, const float* __restrict__ f2b,
       float* __restrict__ out) {
    __shared__ float vals[NPG];
    __shared__ int sel[K_TOP];
    __shared__ float tk[K_TOP * 132];
    __shared__ float wl1[16 * 129];
    __shared__ float y1[16][36];
    __shared__ float y2[16][17];
    __shared__ float y3[416];
    __shared__ float y4[128];
    __shared__ float r2[128];
    int g = blockIdx.x, t = threadIdx.x;
    const float* fg = feat + (size_t)g * NPG * 128;

    for (int i = t; i < 2048; i += 256)
        wl1[(i >> 7) * 129 + (i & 127)] = c1w[i];
    if (t < NPG) vals[t] = fg[t * 128 + 127];
    __syncthreads();
    // stable descending rank (matches stable argsort(-v))
    if (t < NPG) {
        float v = vals[t];
        int r = 0;
        for (int j = 0; j < NPG; j++) {
            float u = vals[j];
            r += (u > v) || (u == v && j < t);
        }
        if (r < K_TOP) sel[r] = t;
    }
    __syncthreads();
    for (int i = t; i < K_TOP * 32; i += 256) {
        int k = i >> 5, c4 = i & 31;
        *(float4*)&tk[k * 132 + 4 * c4] = *(const float4*)&fg[sel[k] * 128 + 4 * c4];
    }
    __syncthreads();
    // conv1 (1x1), weights from LDS
    for (int i = t; i < 16 * K_TOP; i += 256) {
        int o = i & 15, k = i >> 4;
        float s = c1b[o];
        const float* wr = &wl1[o * 129];
        const float* xr = &tk[k * 132];
#pragma unroll 8
        for (int c = 0; c < 128; c++) s += wr[c] * xr[c];
        y1[o][k] = fmaxf(s, 0.f);
    }
    __syncthreads();
    // maxpool1d(2): 35 -> 17
    for (int i = t; i < 16 * 17; i += 256) {
        int o = i & 15, l = i >> 4;
        y2[o][l] = fmaxf(y1[o][2 * l], y1[o][2 * l + 1]);
    }
    __syncthreads();
    // conv2 (k=5, VALID): [16,17] -> [32,13]
    for (int idx = t; idx < 32 * 13; idx += 256) {
        int o2 = idx / 13, ttp = idx - o2 * 13;
        float s = c2b[o2];
        const float* wr = c2w + o2 * 80;
#pragma unroll
        for (int i = 0; i < 16; i++)
#pragma unroll
            for (int j = 0; j < 5; j++) s += wr[i * 5 + j] * y2[i][ttp + j];
        y3[idx] = fmaxf(s, 0.f);
    }
    __syncthreads();
    // fc1: 416 -> 128, 2 threads per output, float4 weight loads
    {
        int o = t >> 1, h = t & 1;
        const float4* wr4 = (const float4*)(f1w + o * 416) + h * 52;
        const float* yb = y3 + h * 208;
        float s = 0.f;
#pragma unroll 4
        for (int i = 0; i < 52; i++) {
            float4 w4 = wr4[i];
            s += w4.x * yb[4 * i] + w4.y * yb[4 * i + 1] +
                 w4.z * yb[4 * i + 2] + w4.w * yb[4 * i + 3];
        }
        s += __shfl_xor(s, 1);
        if (h == 0) y4[o] = fmaxf(s + f1b[o], 0.f);
    }
    __syncthreads();
    if (t < 128) r2[t] = f2w[t] * y4[t];
    __syncthreads();
    for (int off = 64; off > 0; off >>= 1) {
        if (t < off) r2[t] += r2[t + off];
        __syncthreads();
    }
    if (t == 0) out[g] = 1.0f / (1.0f + expf(-(r2[0] + f2b[0])));
}

// ---------------- launch ----------------

static inline size_t alignup(size_t x) { return (x + 255) & ~(size_t)255; }

extern "C" void kernel_launch(void* const* d_in, const int* in_sizes, int n_in,
                              void* d_out, int out_size, void* d_ws, size_t ws_size,
                              hipStream_t stream) {
    const float* x    = (const float*)d_in[0];
    const int*   ei   = (const int*)d_in[1];
    const int*   srcp = ei;
    const int*   dstp = ei + N_EDGES;
    const float* w0 = (const float*)d_in[3];
    const float* b0 = (const float*)d_in[4];
    const float* w1 = (const float*)d_in[5];
    const float* b1 = (const float*)d_in[6];
    const float* w2 = (const float*)d_in[7];
    const float* b2 = (const float*)d_in[8];
    const float* w3 = (const float*)d_in[9];
    const float* b3 = (const float*)d_in[10];
    const float* c1w = (const float*)d_in[11];
    const float* c1b = (const float*)d_in[12];
    const float* c2w = (const float*)d_in[13];
    const float* c2b = (const float*)d_in[14];
    const float* f1w = (const float*)d_in[15];
    const float* f1b = (const float*)d_in[16];
    const float* f2w = (const float*)d_in[17];
    const float* f2b = (const float*)d_in[18];
    float* out = (float*)d_out;

    char* p = (char*)d_ws;
    int2* rcv    = (int2*)p; p += alignup(sizeof(int2) * N_NODES);
    float* dis   = (float*)p; p += alignup(sizeof(float) * N_NODES);
    int* bcnt    = (int*)p; p += alignup(sizeof(int) * NBUCK);
    int* csr     = (int*)p; p += alignup(sizeof(int) * (size_t)NBUCK * CAP);
    // union region: bdata (dead after k_build) aliases the two fp16 hs buffers.
    // Each hs buffer gets ONE extra zeroed sentinel row at index N_NODES.
    char* U = p;
    unsigned int* bdata = (unsigned int*)U;
    char* hsA = U;                                             // 6.4 MB fp16 + 64B sentinel
    char* hsB = U + alignup((size_t)N_NODES * 64 + 64);        // 6.4 MB fp16 + 64B sentinel
    size_t usz = alignup(sizeof(unsigned int) * (size_t)NBUCK * CAP); // 13.65 MB
    float* feat = (float*)(U + usz);

    const int NB_M = (N_NODES + 511) / 512;        // 196 (2 nodes/thread)
    const int NB_A = (N_NODES * 32) / 256;         // 12500 (exact, half-wave per node)

    hipMemsetAsync(bcnt, 0, sizeof(int) * NBUCK, stream);
    k_bin<<<NBB, 256, 0, stream>>>(srcp, dstp, bcnt, bdata);
    k_build<<<NBUCK, 1024, 0, stream>>>(bdata, bcnt, rcv, dis, csr);

    // k_mm0 zeroes both sentinel rows (saves 2 memset dispatches ~9 us)
    k_mm0<<<NB_M, 256, 0, stream>>>(x, w0, dis, hsA, hsB);
    k_agg<<<NB_A, 256, 0, stream>>>((const float4*)hsA, dis, rcv, csr, b0,
                                    feat, 0, w1, hsB);
    k_agg<<<NB_A, 256, 0, stream>>>((const float4*)hsB, dis, rcv, csr, b1,
                                    feat, 32, w2, hsA);
    k_agg<<<NB_A, 256, 0, stream>>>((const float4*)hsA, dis, rcv, csr, b2,
                                    feat, 64, w3, hsB);
    k_agg<<<NB_A, 256, 0, stream>>>((const float4*)hsB, dis, rcv, csr, b3,
                                    feat, 96, (const float*)nullptr, (char*)nullptr);

    k_head<<<N_GRAPHS, 256, 0, stream>>>(feat, c1w, c1b, c2w, c2b,
                                         f1w, f1b, f2w, f2b, out);
}